// Round 13
// baseline (1049.560 us; speedup 1.0000x reference)
//
#include <hip/hip_runtime.h>
#include <hip/hip_bf16.h>

#define B_ 4
#define N_ 4096
#define C_ 256
#define P_ 1024
#define S_ 64
#define HST 264   // H LDS k-stride (bf16 elems); 528B rows -> 2-way (free) frag reads
#define WKR 256   // worker blocks

typedef __attribute__((ext_vector_type(8))) short short8;
typedef __attribute__((ext_vector_type(4))) float f32x4;

__device__ __forceinline__ float rn_mul(float a, float b){ return __fmul_rn(a,b); }
__device__ __forceinline__ float rn_add(float a, float b){ return __fadd_rn(a,b); }
__device__ __forceinline__ float rn_sub(float a, float b){ return __fsub_rn(a,b); }

__device__ __forceinline__ unsigned short f2bf(float x){ // RNE f32->bf16
  union { float f; unsigned u; } v; v.f = x;
  unsigned r = v.u + 0x7fffu + ((v.u >> 16) & 1u);
  return (unsigned short)(r >> 16);
}

// v_max with a DPP-permuted copy; OOB/disabled lanes contribute 0 (safe: dists >= 0)
#define DPPMAX(m, ctrl) \
  m = fmaxf(m, __int_as_float(__builtin_amdgcn_update_dpp(0, __float_as_int(m), ctrl, 0xF, 0xF, true)))

// r12 structure + ONE change: fps publishes winner indices in batches of 8
// (LDS-accumulated, 4x u64 relaxed agent atomic stores once per 8 iterations,
// issued at iteration top so the L3 ack hides under the iteration) instead of
// one agent atomic store per iteration (whose vmcnt(0) drain before s_barrier
// cost ~900 cy/iter).
__global__ __launch_bounds__(256) void fused_kernel(
    const float* __restrict__ xyz, const float* __restrict__ feat,
    const float* __restrict__ rot,
    const float* __restrict__ W1, const float* __restrict__ b1,
    const float* __restrict__ W2, const float* __restrict__ b2,
    float* __restrict__ out,
    unsigned short* __restrict__ featT,
    unsigned short* __restrict__ Wp1, unsigned short* __restrict__ Wp2,
    int* __restrict__ gWidx, int* __restrict__ ftdone)
{
  __shared__ __align__(16) char shm[53408];
  const int gid = blockIdx.x;
  const int t = threadIdx.x;

  if (gid < B_){
    // ---------------- FPS: one block/batch, 4 waves x 16 pts (r9-exact core) ----------------
    __builtin_amdgcn_s_setprio(3);
    float*  xl    = (float*)shm;                          // 48 KB point store
    float4* cand  = (float4*)(shm + N_*3*4);              // [2][4] value+coords
    int*    candI = (int*)(shm + N_*3*4 + 128);           // [2][4] winner indices
    int*    locI  = (int*)(shm + N_*3*4 + 160);           // 4 KB winner-index staging
    const int b = gid;
    const int lane = t & 63, w = t >> 6;                  // 4 waves
    const float* xb = xyz + (size_t)b*N_*3;
    {
      float4* dst = (float4*)xl; const float4* src = (const float4*)xb;
      for (int i = t; i < N_*3/4; i += 256) dst[i] = src[i];
    }
    if (t == 0) locI[0] = 0;                              // farthest_0 = 0
    __syncthreads();
    float px[16], py[16], pz[16], dist[16];
    {
      float buf[48];
      #pragma unroll
      for (int i=0;i<12;i++){
        const float4 v = *(const float4*)&xl[t*48 + i*4];
        buf[i*4+0]=v.x; buf[i*4+1]=v.y; buf[i*4+2]=v.z; buf[i*4+3]=v.w;
      }
      #pragma unroll
      for (int j=0;j<16;j++){
        px[j]=buf[j*3+0]; py[j]=buf[j*3+1]; pz[j]=buf[j*3+2];
        dist[j] = 1e10f;
      }
    }
    float cx = xl[0], cy = xl[1], cz = xl[2];             // farthest_0 = 0
    for (int it=0; it<P_; ++it){
      // ---- batched publish (top of iter: ack hides under this iteration) ----
      if (t == 0 && (it & 7) == 0 && it > 0){
        const int base = it - 8;
        const uint4 a = *(const uint4*)&locI[base];
        const uint4 c = *(const uint4*)&locI[base + 4];
        unsigned long long* g = (unsigned long long*)&gWidx[b*P_ + base];
        __hip_atomic_store(&g[0], ((unsigned long long)a.y << 32) | a.x, __ATOMIC_RELAXED, __HIP_MEMORY_SCOPE_AGENT);
        __hip_atomic_store(&g[1], ((unsigned long long)a.w << 32) | a.z, __ATOMIC_RELAXED, __HIP_MEMORY_SCOPE_AGENT);
        __hip_atomic_store(&g[2], ((unsigned long long)c.y << 32) | c.x, __ATOMIC_RELAXED, __HIP_MEMORY_SCOPE_AGENT);
        __hip_atomic_store(&g[3], ((unsigned long long)c.w << 32) | c.z, __ATOMIC_RELAXED, __HIP_MEMORY_SCOPE_AGENT);
      }
      float bestv = -1.f; int bestj = 0;
      #pragma unroll
      for (int j=0;j<16;j++){
        const float dx = rn_sub(px[j],cx), dy = rn_sub(py[j],cy), dz = rn_sub(pz[j],cz);
        const float d  = rn_add(rn_add(rn_mul(dx,dx), rn_mul(dy,dy)), rn_mul(dz,dz));
        const float nd = fminf(dist[j], d);
        dist[j] = nd;
        if (nd > bestv){ bestv = nd; bestj = j; }   // strict > keeps first (lowest j)
      }
      float m = bestv;
      DPPMAX(m, 0x111);  // row_shr:1
      DPPMAX(m, 0x112);  // row_shr:2
      DPPMAX(m, 0x114);  // row_shr:4
      DPPMAX(m, 0x118);  // row_shr:8
      DPPMAX(m, 0x142);  // row_bcast:15
      DPPMAX(m, 0x143);  // row_bcast:31
      const float ms = __int_as_float(__builtin_amdgcn_readlane(__float_as_int(m), 63));
      const unsigned long long bal = __ballot(bestv == ms);
      const int winlane = __ffsll((long long)bal) - 1;        // lowest lane = lowest index
      const int widx = __builtin_amdgcn_readlane(t*16 + bestj, winlane) & ~15;
      const int wj   = __builtin_amdgcn_readlane(bestj, winlane);
      const int pb = it & 1;                                   // double buffer (skew <= 1)
      if (lane == 0){
        const float* cp = xl + (size_t)(widx + wj)*3;
        cand[pb*4 + w] = make_float4(ms, cp[0], cp[1], cp[2]);
        candI[pb*4 + w] = widx + wj;
      }
      __syncthreads();
      // keep-first scan over 4 wave candidates (ascending wave id)
      const float4 c0 = cand[pb*4+0], c1 = cand[pb*4+1], c2 = cand[pb*4+2], c3 = cand[pb*4+3];
      const int i0 = candI[pb*4+0], i1 = candI[pb*4+1], i2 = candI[pb*4+2], i3 = candI[pb*4+3];
      float fv = c0.x; cx = c0.y; cy = c0.z; cz = c0.w; int fi = i0;
      if (c1.x > fv){ fv = c1.x; cx = c1.y; cy = c1.z; cz = c1.w; fi = i1; }
      if (c2.x > fv){ fv = c2.x; cx = c2.y; cy = c2.z; cz = c2.w; fi = i2; }
      if (c3.x > fv){ fv = c3.x; cx = c3.y; cy = c3.z; cz = c3.w; fi = i3; }
      if (t == 0 && it + 1 < P_) locI[it + 1] = fi;            // LDS only, no drain
    }
    // final batch: locI[1016..1023]
    if (t == 0){
      const int base = P_ - 8;
      const uint4 a = *(const uint4*)&locI[base];
      const uint4 c = *(const uint4*)&locI[base + 4];
      unsigned long long* g = (unsigned long long*)&gWidx[b*P_ + base];
      __hip_atomic_store(&g[0], ((unsigned long long)a.y << 32) | a.x, __ATOMIC_RELAXED, __HIP_MEMORY_SCOPE_AGENT);
      __hip_atomic_store(&g[1], ((unsigned long long)a.w << 32) | a.z, __ATOMIC_RELAXED, __HIP_MEMORY_SCOPE_AGENT);
      __hip_atomic_store(&g[2], ((unsigned long long)c.y << 32) | c.x, __ATOMIC_RELAXED, __HIP_MEMORY_SCOPE_AGENT);
      __hip_atomic_store(&g[3], ((unsigned long long)c.w << 32) | c.z, __ATOMIC_RELAXED, __HIP_MEMORY_SCOPE_AGENT);
    }
    __builtin_amdgcn_s_setprio(0);
  } else {
    // ================= worker block (priority 0) =================
    const int wk = gid - B_;            // 0..255
    const int b  = wk >> 6;             // 64 workers per batch
    // ---- phase 1: feature transpose, 16 tiles ----
    {
      float (*tile)[33] = (float (*)[33])shm;
      const int tx = t & 31, ty = t >> 5;  // 32x8
      for (int i=0;i<16;i++){
        const int idx = wk*16 + i;
        const int nx = idx & 127, cyi = (idx >> 7) & 7, bz = idx >> 10;
        const int n0 = nx*32, c0 = cyi*32;
        #pragma unroll
        for (int j=0;j<4;j++)
          tile[ty + j*8][tx] = feat[((size_t)bz*C_ + (size_t)(c0+ty+j*8))*N_ + n0 + tx];
        __syncthreads();
        #pragma unroll
        for (int j=0;j<4;j++)
          featT[((size_t)bz*N_ + (size_t)(n0+ty+j*8))*C_ + c0 + tx] = f2bf(tile[tx][ty + j*8]);
        __syncthreads();
      }
    }
    // ---- wprep row o = wk ----
    {
      const int o = wk;
      Wp1[o*288 + t] = f2bf(W1[o*259 + 3 + t]);
      if (t < 32){
        float v = (t < 3) ? W1[o*259 + t] : 0.f;
        Wp1[o*288 + 256 + t] = f2bf(v);
      }
      Wp2[o*256 + t] = f2bf(W2[o*256 + t]);
    }
    __threadfence();                     // write back dirty L2 lines (featT/Wp)
    __syncthreads();
    if (t == 0)
      __hip_atomic_fetch_add(ftdone, 1, __ATOMIC_RELEASE, __HIP_MEMORY_SCOPE_AGENT);

    // ---- phase 2 LDS layout ----
    unsigned short* Hlds = (unsigned short*)shm;                       // 33792 B
    int*            sI   = (int*)(shm + 64*HST*2);                     // 256 B
    unsigned short* rotP = (unsigned short*)(shm + 64*HST*2 + 256);    // 1024 B
    int*            sWi  = (int*)(shm + 64*HST*2 + 256 + 1024);        // 4 B

    const int lane = t & 63, wv = t >> 6;
    const int l15 = lane & 15, q = lane >> 4;
    bool ftOK = false;

    for (int k=0;k<16;k++){
      const int p = (wk & 63) + 64*k;
      const int bp = b*P_ + p;
      // ---- wait for fps to publish centroid index p ----
      if (t == 0){
        int wi;
        while ((wi = __hip_atomic_load(&gWidx[bp], __ATOMIC_RELAXED, __HIP_MEMORY_SCOPE_AGENT)) == -1)
          __builtin_amdgcn_s_sleep(64);
        *sWi = wi;
      }
      __syncthreads();
      const int wi = *sWi;
      // ---- cylinder query (wave 0), outputs to LDS ----
      if (wv == 0){
        const float* xb = xyz + (size_t)b*N_*3;
        const float* r9 = rot + (size_t)bp*9;
        const float R0=r9[0],R1=r9[1],R2=r9[2],R3=r9[3],R4=r9[4],R5=r9[5],R6=r9[6],R7=r9[7],R8=r9[8];
        const float nx = xb[wi*3+0], ny = xb[wi*3+1], nz = xb[wi*3+2];
        const float thr = R2;   // replicate the reference's r2-shadowing bug
        int filled = 0;
        float p0r0=0.f, p0r1=0.f, p0r2=0.f;
        for (int base = 0; base < N_; base += 64){
          const int n = base + lane;
          const float dx = rn_sub(xb[n*3+0], nx);
          const float dy = rn_sub(xb[n*3+1], ny);
          const float dz = rn_sub(xb[n*3+2], nz);
          const float r0 = rn_add(rn_add(rn_mul(dx,R0), rn_mul(dy,R3)), rn_mul(dz,R6));
          const float r1 = rn_add(rn_add(rn_mul(dx,R1), rn_mul(dy,R4)), rn_mul(dz,R7));
          const float r2 = rn_add(rn_add(rn_mul(dx,R2), rn_mul(dy,R5)), rn_mul(dz,R8));
          if (base == 0){
            p0r0 = __shfl(r0, 0, 64); p0r1 = __shfl(r1, 0, 64); p0r2 = __shfl(r2, 0, 64);
          }
          const float d2 = rn_add(rn_mul(r1,r1), rn_mul(r2,r2));
          const bool mq = (d2 < thr) & (r0 > -0.02f) & (r0 < 0.04f);
          const unsigned long long bal = __ballot(mq);
          const int before = (int)__popcll(bal & ((1ull << lane) - 1ull));
          const int slot = filled + before;
          if (mq && slot < S_){
            sI[slot] = n;
            uint4 u;
            u.x = (unsigned)f2bf(r0) | ((unsigned)f2bf(r1) << 16);
            u.y = (unsigned)f2bf(r2);
            u.z = 0u; u.w = 0u;
            *(uint4*)&rotP[slot*8] = u;
          }
          filled += (int)__popcll(bal);
          if (filled >= S_) break;
        }
        if (filled < S_){
          const int slot = filled + lane;
          if (slot < S_){
            sI[slot] = 0;
            uint4 u;
            u.x = (unsigned)f2bf(p0r0) | ((unsigned)f2bf(p0r1) << 16);
            u.y = (unsigned)f2bf(p0r2);
            u.z = 0u; u.w = 0u;
            *(uint4*)&rotP[slot*8] = u;
          }
        }
      }
      __syncthreads();
      // ---- gate first mlp on featT/Wp completion (once per block) ----
      if (!ftOK){
        if (t == 0){
          while (__hip_atomic_load(ftdone, __ATOMIC_RELAXED, __HIP_MEMORY_SCOPE_AGENT) != WKR)
            __builtin_amdgcn_s_sleep(64);
        }
        __syncthreads();
        __builtin_amdgcn_fence(__ATOMIC_ACQUIRE, "agent");   // invalidate stale lines
        ftOK = true;
      }
      // ---- 1-pt MFMA mlp (bit-identical accumulation order to proven 2-pt kernel) ----
      {
        unsigned rowOff[4];
        #pragma unroll
        for (int st=0; st<4; ++st){
          const int s = st*16 + l15;
          const int row = sI[s];
          rowOff[st] = (unsigned)(((b*N_ + row)*C_ + q*8) * 2);
        }
        const char* fbase = (const char*)featT;
        f32x4 acc[4][4];
        #pragma unroll
        for (int at=0; at<4; ++at){
          const float4 bv = *(const float4*)(b1 + wv*64 + at*16 + q*4);
          #pragma unroll
          for (int st=0; st<4; ++st){
            acc[at][st][0]=bv.x; acc[at][st][1]=bv.y; acc[at][st][2]=bv.z; acc[at][st][3]=bv.w;
          }
        }
        const unsigned short* wb1 = Wp1 + (size_t)(wv*64 + l15)*288 + q*8;
        #pragma unroll
        for (int ks=0; ks<8; ++ks){
          short8 a[4], x[4];
          #pragma unroll
          for (int at=0; at<4; ++at) a[at] = *(const short8*)(wb1 + at*16*288 + ks*32);
          #pragma unroll
          for (int st=0; st<4; ++st) x[st] = *(const short8*)(fbase + rowOff[st] + ks*64);
          #pragma unroll
          for (int at=0; at<4; ++at)
            #pragma unroll
            for (int st=0; st<4; ++st)
              acc[at][st] = __builtin_amdgcn_mfma_f32_16x16x32_bf16(a[at], x[st], acc[at][st], 0,0,0);
        }
        { // K-step 8: rot fragments from LDS, rest zero
          short8 a[4], x[4];
          #pragma unroll
          for (int at=0; at<4; ++at) a[at] = *(const short8*)(wb1 + at*16*288 + 8*32);
          #pragma unroll
          for (int st=0; st<4; ++st){
            short8 v = (short8){0,0,0,0,0,0,0,0};
            if (q == 0) v = *(const short8*)&rotP[(st*16 + l15)*8];
            x[st] = v;
          }
          #pragma unroll
          for (int at=0; at<4; ++at)
            #pragma unroll
            for (int st=0; st<4; ++st)
              acc[at][st] = __builtin_amdgcn_mfma_f32_16x16x32_bf16(a[at], x[st], acc[at][st], 0,0,0);
        }
        // relu -> bf16 -> Hlds[s][o]
        #pragma unroll
        for (int at=0; at<4; ++at)
          #pragma unroll
          for (int st=0; st<4; ++st){
            const int s = st*16 + l15;
            const int o = wv*64 + at*16 + q*4;
            const unsigned h0 = f2bf(fmaxf(acc[at][st][0], 0.f));
            const unsigned h1 = f2bf(fmaxf(acc[at][st][1], 0.f));
            const unsigned h2 = f2bf(fmaxf(acc[at][st][2], 0.f));
            const unsigned h3 = f2bf(fmaxf(acc[at][st][3], 0.f));
            uint2 u; u.x = h0 | (h1 << 16); u.y = h2 | (h3 << 16);
            *(uint2*)&Hlds[s*HST + o] = u;
          }
        __syncthreads();
        // layer 2
        #pragma unroll
        for (int at=0; at<4; ++at){
          const float4 bv = *(const float4*)(b2 + wv*64 + at*16 + q*4);
          #pragma unroll
          for (int st=0; st<4; ++st){
            acc[at][st][0]=bv.x; acc[at][st][1]=bv.y; acc[at][st][2]=bv.z; acc[at][st][3]=bv.w;
          }
        }
        const unsigned short* wb2 = Wp2 + (size_t)(wv*64 + l15)*256 + q*8;
        #pragma unroll
        for (int ks=0; ks<8; ++ks){
          short8 a[4], h[4];
          #pragma unroll
          for (int at=0; at<4; ++at) a[at] = *(const short8*)(wb2 + at*16*256 + ks*32);
          #pragma unroll
          for (int st=0; st<4; ++st)
            h[st] = *(const short8*)&Hlds[(st*16 + l15)*HST + ks*32 + q*8];
          #pragma unroll
          for (int at=0; at<4; ++at)
            #pragma unroll
            for (int st=0; st<4; ++st)
              acc[at][st] = __builtin_amdgcn_mfma_f32_16x16x32_bf16(a[at], h[st], acc[at][st], 0,0,0);
        }
        // max over s, relu, store
        #pragma unroll
        for (int at=0; at<4; ++at){
          #pragma unroll
          for (int r=0; r<4; ++r){
            float mm = fmaxf(fmaxf(acc[at][0][r], acc[at][1][r]),
                             fmaxf(acc[at][2][r], acc[at][3][r]));
            mm = fmaxf(mm, __shfl_xor(mm, 1, 64));
            mm = fmaxf(mm, __shfl_xor(mm, 2, 64));
            mm = fmaxf(mm, __shfl_xor(mm, 4, 64));
            mm = fmaxf(mm, __shfl_xor(mm, 8, 64));
            mm = fmaxf(mm, 0.f);
            if (l15 == 0){
              const int o = wv*64 + at*16 + q*4 + r;
              out[((size_t)b*256 + o)*P_ + p] = mm;
            }
          }
        }
      }
      __syncthreads();   // before next k reuses sI/rotP/Hlds
    }
  }
}

extern "C" void kernel_launch(void* const* d_in, const int* in_sizes, int n_in,
                              void* d_out, int out_size, void* d_ws, size_t ws_size,
                              hipStream_t stream)
{
  const float* xyz  = (const float*)d_in[0];
  const float* feat = (const float*)d_in[1];
  const float* rot  = (const float*)d_in[2];
  const float* W1   = (const float*)d_in[3];
  const float* b1   = (const float*)d_in[4];
  const float* W2   = (const float*)d_in[5];
  const float* b2   = (const float*)d_in[6];
  float* out = (float*)d_out;

  char* ws = (char*)d_ws;
  unsigned short* featT = (unsigned short*)(ws);
  size_t off = (size_t)B_*N_*C_*2;                                   // 8.39 MB
  unsigned short* Wp1 = (unsigned short*)(ws + off); off += (size_t)256*288*2;
  unsigned short* Wp2 = (unsigned short*)(ws + off); off += (size_t)256*256*2;
  int* gWidx  = (int*)(ws + off); off += (size_t)B_*P_*4;            // 16 KB
  int* ftdone = (int*)(ws + off); off += 16;
  (void)ws_size; (void)in_sizes; (void)n_in; (void)out_size;

  hipMemsetAsync(gWidx, 0xFF, (size_t)B_*P_*4, stream);   // -1 sentinels (deterministic)
  hipMemsetAsync(ftdone, 0, 4, stream);
  hipLaunchKernelGGL(fused_kernel, dim3(B_ + WKR), dim3(256), 0, stream,
                     xyz, feat, rot, W1, b1, W2, b2, out,
                     featT, Wp1, Wp2, gWidx, ftdone);
}

// Round 14
// 814.554 us; speedup vs baseline: 1.2885x; 1.2885x over previous
//
#include <hip/hip_runtime.h>
#include <hip/hip_bf16.h>

#define B_ 4
#define N_ 4096
#define C_ 256
#define P_ 1024
#define S_ 64
#define HST 264   // H LDS k-stride (bf16 elems); 528B rows -> 2-way (free) frag reads

typedef __attribute__((ext_vector_type(8))) short short8;
typedef __attribute__((ext_vector_type(4))) float f32x4;

__device__ __forceinline__ float rn_mul(float a, float b){ return __fmul_rn(a,b); }
__device__ __forceinline__ float rn_add(float a, float b){ return __fadd_rn(a,b); }
__device__ __forceinline__ float rn_sub(float a, float b){ return __fsub_rn(a,b); }

__device__ __forceinline__ unsigned short f2bf(float x){ // RNE f32->bf16
  union { float f; unsigned u; } v; v.f = x;
  unsigned r = v.u + 0x7fffu + ((v.u >> 16) & 1u);
  return (unsigned short)(r >> 16);
}

// v_max with a DPP-permuted copy; OOB/disabled lanes contribute 0 (safe: dists >= 0)
#define DPPMAX(m, ctrl) \
  m = fmaxf(m, __int_as_float(__builtin_amdgcn_update_dpp(0, __float_as_int(m), ctrl, 0xF, 0xF, true)))

// ---------------- fused pre-kernel: fps (blocks 0..3) + wprep (4..259) + ftrans (260..4355) ----
// r9-exact (measured 630 us): fps path is the r4 657-us kernel; ftrans/wprep have no
// dependency on fps and run concurrently on other CUs, hidden inside the fps shadow.
__global__ __launch_bounds__(256, 1) void pre_kernel(
    const float* __restrict__ xyz, float* __restrict__ newXyz,
    const float* __restrict__ f, unsigned short* __restrict__ ft,
    const float* __restrict__ W1, const float* __restrict__ W2,
    unsigned short* __restrict__ Wp1, unsigned short* __restrict__ Wp2)
{
  __shared__ __align__(16) char shm[N_*3*4 + 8*16];
  const int gid = blockIdx.x;
  const int t = threadIdx.x;

  if (gid < B_){
    // ---------------- FPS: one block/batch, 4 waves x 16 pts (r4 exact) ----------------
    // Exact fp32 distance semantics (_rn chain, left-fold). First-occurrence argmax:
    // lane-local keep-first (strict >, ascending j) -> lowest lane of value-match ballot
    // (lanes own contiguous ascending ranges) -> ascending-wave keep-first scan.
    float* xl = (float*)shm;                      // 48 KB point store
    float4* cand = (float4*)(shm + N_*3*4);       // [2][4] double-buffered candidates
    const int b = gid;
    const int lane = t & 63, w = t >> 6;          // 4 waves
    const float* xb = xyz + (size_t)b*N_*3;
    {
      float4* dst = (float4*)xl; const float4* src = (const float4*)xb;
      for (int i = t; i < N_*3/4; i += 256) dst[i] = src[i];
    }
    __syncthreads();
    float px[16], py[16], pz[16], dist[16];
    {
      float buf[48];
      #pragma unroll
      for (int i=0;i<12;i++){
        const float4 v = *(const float4*)&xl[t*48 + i*4];
        buf[i*4+0]=v.x; buf[i*4+1]=v.y; buf[i*4+2]=v.z; buf[i*4+3]=v.w;
      }
      #pragma unroll
      for (int j=0;j<16;j++){
        px[j]=buf[j*3+0]; py[j]=buf[j*3+1]; pz[j]=buf[j*3+2];
        dist[j] = 1e10f;
      }
    }
    float cx = xl[0], cy = xl[1], cz = xl[2];     // farthest_0 = 0
    for (int it=0; it<P_; ++it){
      if (t == 0){
        float* nz = newXyz + ((size_t)b*P_ + it)*3;
        nz[0]=cx; nz[1]=cy; nz[2]=cz;
      }
      float bestv = -1.f; int bestj = 0;
      #pragma unroll
      for (int j=0;j<16;j++){
        const float dx = rn_sub(px[j],cx), dy = rn_sub(py[j],cy), dz = rn_sub(pz[j],cz);
        const float d  = rn_add(rn_add(rn_mul(dx,dx), rn_mul(dy,dy)), rn_mul(dz,dz));
        const float nd = fminf(dist[j], d);
        dist[j] = nd;
        if (nd > bestv){ bestv = nd; bestj = j; }   // strict > keeps first (lowest j)
      }
      // wave max of value only, via DPP (VALU pipe, no LDS)
      float m = bestv;
      DPPMAX(m, 0x111);  // row_shr:1
      DPPMAX(m, 0x112);  // row_shr:2
      DPPMAX(m, 0x114);  // row_shr:4
      DPPMAX(m, 0x118);  // row_shr:8
      DPPMAX(m, 0x142);  // row_bcast:15
      DPPMAX(m, 0x143);  // row_bcast:31
      const float ms = __int_as_float(__builtin_amdgcn_readlane(__float_as_int(m), 63));
      const unsigned long long bal = __ballot(bestv == ms);
      const int winlane = __ffsll((long long)bal) - 1;        // lowest lane = lowest index
      const int widx = __builtin_amdgcn_readlane(t*16 + bestj, winlane) & ~15;
      const int wj   = __builtin_amdgcn_readlane(bestj, winlane);
      const int pb = it & 1;                                   // double buffer (skew <= 1)
      if (lane == 0){
        const float* cp = xl + (size_t)(widx + wj)*3;
        cand[pb*4 + w] = make_float4(ms, cp[0], cp[1], cp[2]);
      }
      __syncthreads();
      // keep-first scan over 4 wave candidates (ascending wave id)
      const float4 c0 = cand[pb*4+0], c1 = cand[pb*4+1], c2 = cand[pb*4+2], c3 = cand[pb*4+3];
      float fv = c0.x; cx = c0.y; cy = c0.z; cz = c0.w;
      if (c1.x > fv){ fv = c1.x; cx = c1.y; cy = c1.z; cz = c1.w; }
      if (c2.x > fv){ fv = c2.x; cx = c2.y; cy = c2.z; cz = c2.w; }
      if (c3.x > fv){ fv = c3.x; cx = c3.y; cy = c3.z; cz = c3.w; }
    }
  } else if (gid < B_ + 256){
    // ---------------- weight prep: bf16, features-first permutation, zero pad ----------------
    const int o = gid - B_;
    Wp1[o*288 + t] = f2bf(W1[o*259 + 3 + t]);
    if (t < 32){
      float v = (t < 3) ? W1[o*259 + t] : 0.f;
      Wp1[o*288 + 256 + t] = f2bf(v);
    }
    Wp2[o*256 + t] = f2bf(W2[o*256 + t]);
  } else {
    // ---------------- feature transpose (B,C,N) f32 -> (B,N,C) bf16 ----------------
    const int idx = gid - (B_ + 256);
    const int nx = idx & 127;            // N_/32 = 128
    const int cyi = (idx >> 7) & 7;      // C_/32 = 8
    const int bz = idx >> 10;
    float (*tile)[33] = (float (*)[33])shm;
    const int n0 = nx*32, c0 = cyi*32;
    const int tx = t & 31, ty = t >> 5;  // 32x8
    #pragma unroll
    for (int j=0;j<4;j++)
      tile[ty + j*8][tx] = f[((size_t)bz*C_ + (size_t)(c0+ty+j*8))*N_ + n0 + tx];
    __syncthreads();
    #pragma unroll
    for (int j=0;j<4;j++)
      ft[((size_t)bz*N_ + (size_t)(n0+ty+j*8))*C_ + c0 + tx] = f2bf(tile[tx][ty + j*8]);
  }
}

// ---------------- MFMA MLP, 2 query points per block, with INTEGRATED cylinder query ----------
// Waves 0/1 each run the (verbatim r9) query for bp0/bp1, writing sI/rotP to LDS;
// then all 4 waves run the proven 2-pt MLP with B-side reads from LDS instead of global.
__global__ __launch_bounds__(256,2) void mlp_kernel(
    const float* __restrict__ xyz,
    const float* __restrict__ rot,
    const float* __restrict__ newXyz,
    const unsigned short* __restrict__ featT, // (B,N,C) bf16
    const unsigned short* __restrict__ Wp1,   // [256][288] bf16
    const float* __restrict__ b1,
    const unsigned short* __restrict__ Wp2,   // [256][256] bf16
    const float* __restrict__ b2,
    float* __restrict__ out)
{
  __shared__ unsigned short Hlds[2][64*HST];           // 67584 B
  __shared__ int sI[2][S_];                            // 512 B
  __shared__ unsigned short rotP[2][S_*8];             // 2048 B
  const int bid = blockIdx.x;
  const int pp = (bid & 7) * 256 + (bid >> 3);  // XCD-chunked swizzle (2048 % 8 == 0)
  const int bp0 = pp*2, bp1 = bp0 + 1;
  const int b = bp0 >> 10, p0 = bp0 & 1023;
  const int t = threadIdx.x;
  const int w = t >> 6, l = t & 63;
  const int l15 = l & 15, q = l >> 4;

  // ---- integrated cylinder query: wave g handles bp0+g (g = 0,1) ----
  if (w < 2){
    const int g = w;
    const int bp = bp0 + g;
    const float* xb = xyz + (size_t)b*N_*3;
    const float* r9 = rot + (size_t)bp*9;
    const float R0=r9[0],R1=r9[1],R2=r9[2],R3=r9[3],R4=r9[4],R5=r9[5],R6=r9[6],R7=r9[7],R8=r9[8];
    const float nx=newXyz[bp*3+0], ny=newXyz[bp*3+1], nz=newXyz[bp*3+2];
    const float thr = R2;   // replicate the reference's r2-shadowing bug
    int filled = 0;
    float p0r0=0.f, p0r1=0.f, p0r2=0.f;
    for (int base = 0; base < N_; base += 64){
      const int n = base + l;
      const float dx = rn_sub(xb[n*3+0], nx);
      const float dy = rn_sub(xb[n*3+1], ny);
      const float dz = rn_sub(xb[n*3+2], nz);
      const float r0 = rn_add(rn_add(rn_mul(dx,R0), rn_mul(dy,R3)), rn_mul(dz,R6));
      const float r1 = rn_add(rn_add(rn_mul(dx,R1), rn_mul(dy,R4)), rn_mul(dz,R7));
      const float r2 = rn_add(rn_add(rn_mul(dx,R2), rn_mul(dy,R5)), rn_mul(dz,R8));
      if (base == 0){
        p0r0 = __shfl(r0, 0, 64); p0r1 = __shfl(r1, 0, 64); p0r2 = __shfl(r2, 0, 64);
      }
      const float d2 = rn_add(rn_mul(r1,r1), rn_mul(r2,r2));
      const bool m = (d2 < thr) & (r0 > -0.02f) & (r0 < 0.04f);
      const unsigned long long bal = __ballot(m);
      const int before = (int)__popcll(bal & ((1ull << l) - 1ull));
      const int slot = filled + before;
      if (m && slot < S_){
        sI[g][slot] = n;
        uint4 u;
        u.x = (unsigned)f2bf(r0) | ((unsigned)f2bf(r1) << 16);
        u.y = (unsigned)f2bf(r2);
        u.z = 0u; u.w = 0u;
        *(uint4*)&rotP[g][slot*8] = u;
      }
      filled += (int)__popcll(bal);
      if (filled >= S_) break;
    }
    if (filled < S_){
      const int slot = filled + l;
      if (slot < S_){
        sI[g][slot] = 0;
        uint4 u;
        u.x = (unsigned)f2bf(p0r0) | ((unsigned)f2bf(p0r1) << 16);
        u.y = (unsigned)f2bf(p0r2);
        u.z = 0u; u.w = 0u;
        *(uint4*)&rotP[g][slot*8] = u;
      }
    }
  }
  __syncthreads();

  // ---- MLP (r9-exact accumulation order) ----
  unsigned rowOff[8];
  #pragma unroll
  for (int st=0; st<8; ++st){
    const int s = (st & 3)*16 + l15;
    const int row = sI[st >> 2][s];
    rowOff[st] = (unsigned)(((b*N_ + row)*C_ + q*8) * 2);
  }
  const char* fbase = (const char*)featT;

  f32x4 acc[4][8];
  #pragma unroll
  for (int at=0; at<4; ++at){
    const float4 bv = *(const float4*)(b1 + w*64 + at*16 + q*4);
    #pragma unroll
    for (int st=0; st<8; ++st){
      acc[at][st][0]=bv.x; acc[at][st][1]=bv.y; acc[at][st][2]=bv.z; acc[at][st][3]=bv.w;
    }
  }

  // ---- layer 1: K = 288 (8 feature K-steps + 1 rot/pad K-step) ----
  const unsigned short* wb1 = Wp1 + (size_t)(w*64 + l15)*288 + q*8;
  #pragma unroll
  for (int ks=0; ks<8; ++ks){
    short8 a[4], x[8];
    #pragma unroll
    for (int at=0; at<4; ++at) a[at] = *(const short8*)(wb1 + at*16*288 + ks*32);
    #pragma unroll
    for (int st=0; st<8; ++st) x[st] = *(const short8*)(fbase + rowOff[st] + ks*64);
    #pragma unroll
    for (int at=0; at<4; ++at)
      #pragma unroll
      for (int st=0; st<8; ++st)
        acc[at][st] = __builtin_amdgcn_mfma_f32_16x16x32_bf16(a[at], x[st], acc[at][st], 0,0,0);
  }
  { // K-step 8: k=256..258 are rot_d (prepacked bf16 fragments in LDS), k>=259 zero
    short8 a[4], x[8];
    #pragma unroll
    for (int at=0; at<4; ++at) a[at] = *(const short8*)(wb1 + at*16*288 + 8*32);
    #pragma unroll
    for (int st=0; st<8; ++st){
      short8 v = (short8){0,0,0,0,0,0,0,0};
      if (q == 0){
        const int s = (st & 3)*16 + l15;
        v = *(const short8*)&rotP[st >> 2][s*8];
      }
      x[st] = v;
    }
    #pragma unroll
    for (int at=0; at<4; ++at)
      #pragma unroll
      for (int st=0; st<8; ++st)
        acc[at][st] = __builtin_amdgcn_mfma_f32_16x16x32_bf16(a[at], x[st], acc[at][st], 0,0,0);
  }

  // ---- relu -> bf16 -> Hlds[p][s][o] ----
  #pragma unroll
  for (int at=0; at<4; ++at)
    #pragma unroll
    for (int st=0; st<8; ++st){
      const int s = (st & 3)*16 + l15;
      const int o = w*64 + at*16 + q*4;
      const unsigned h0 = f2bf(fmaxf(acc[at][st][0], 0.f));
      const unsigned h1 = f2bf(fmaxf(acc[at][st][1], 0.f));
      const unsigned h2 = f2bf(fmaxf(acc[at][st][2], 0.f));
      const unsigned h3 = f2bf(fmaxf(acc[at][st][3], 0.f));
      uint2 u; u.x = h0 | (h1 << 16); u.y = h2 | (h3 << 16);
      *(uint2*)&Hlds[st >> 2][s*HST + o] = u;
    }
  __syncthreads();

  // ---- layer 2: K = 256, B-frags from Hlds ----
  #pragma unroll
  for (int at=0; at<4; ++at){
    const float4 bv = *(const float4*)(b2 + w*64 + at*16 + q*4);
    #pragma unroll
    for (int st=0; st<8; ++st){
      acc[at][st][0]=bv.x; acc[at][st][1]=bv.y; acc[at][st][2]=bv.z; acc[at][st][3]=bv.w;
    }
  }
  const unsigned short* wb2 = Wp2 + (size_t)(w*64 + l15)*256 + q*8;
  #pragma unroll
  for (int ks=0; ks<8; ++ks){
    short8 a[4], h[8];
    #pragma unroll
    for (int at=0; at<4; ++at) a[at] = *(const short8*)(wb2 + at*16*256 + ks*32);
    #pragma unroll
    for (int st=0; st<8; ++st)
      h[st] = *(const short8*)&Hlds[st >> 2][((st & 3)*16 + l15)*HST + ks*32 + q*8];
    #pragma unroll
    for (int at=0; at<4; ++at)
      #pragma unroll
      for (int st=0; st<8; ++st)
        acc[at][st] = __builtin_amdgcn_mfma_f32_16x16x32_bf16(a[at], h[st], acc[at][st], 0,0,0);
  }

  // ---- max over s per p, relu, store ----
  #pragma unroll
  for (int g=0; g<2; ++g){
    const int p = p0 + g;
    #pragma unroll
    for (int at=0; at<4; ++at){
      #pragma unroll
      for (int r=0; r<4; ++r){
        float m = fmaxf(fmaxf(acc[at][g*4+0][r], acc[at][g*4+1][r]),
                        fmaxf(acc[at][g*4+2][r], acc[at][g*4+3][r]));
        m = fmaxf(m, __shfl_xor(m, 1, 64));
        m = fmaxf(m, __shfl_xor(m, 2, 64));
        m = fmaxf(m, __shfl_xor(m, 4, 64));
        m = fmaxf(m, __shfl_xor(m, 8, 64));
        m = fmaxf(m, 0.f);
        if (l15 == 0){
          const int o = w*64 + at*16 + q*4 + r;
          out[((size_t)b*256 + o)*P_ + p] = m;
        }
      }
    }
  }
}

extern "C" void kernel_launch(void* const* d_in, const int* in_sizes, int n_in,
                              void* d_out, int out_size, void* d_ws, size_t ws_size,
                              hipStream_t stream)
{
  const float* xyz  = (const float*)d_in[0];
  const float* feat = (const float*)d_in[1];
  const float* rot  = (const float*)d_in[2];
  const float* W1   = (const float*)d_in[3];
  const float* b1   = (const float*)d_in[4];
  const float* W2   = (const float*)d_in[5];
  const float* b2   = (const float*)d_in[6];
  float* out = (float*)d_out;

  char* ws = (char*)d_ws;
  unsigned short* featT = (unsigned short*)(ws);
  size_t off = (size_t)B_*N_*C_*2;                                   // 8.39 MB
  float* newXyz = (float*)(ws + off); off += (size_t)B_*P_*3*4;      // 48 KB
  unsigned short* Wp1 = (unsigned short*)(ws + off); off += (size_t)256*288*2;
  unsigned short* Wp2 = (unsigned short*)(ws + off); off += (size_t)256*256*2;
  (void)ws_size; (void)in_sizes; (void)n_in; (void)out_size;

  // fused: fps (4 blocks) + wprep (256 blocks) + ftrans (4096 blocks)
  hipLaunchKernelGGL(pre_kernel, dim3(B_ + 256 + 4096), dim3(256), 0, stream,
                     xyz, newXyz, feat, featT, W1, W2, Wp1, Wp2);
  // query integrated into mlp (waves 0/1 per block)
  hipLaunchKernelGGL(mlp_kernel, dim3(B_*P_/2), dim3(256), 0, stream,
                     xyz, rot, newXyz, featT, Wp1, b1, Wp2, b2, out);
}

// Round 15
// 662.783 us; speedup vs baseline: 1.5836x; 1.2290x over previous
//
#include <hip/hip_runtime.h>
#include <hip/hip_bf16.h>

#define B_ 4
#define N_ 4096
#define C_ 256
#define P_ 1024
#define S_ 64
#define HST 264   // H LDS k-stride (bf16 elems); 528B rows -> 2-way (free) frag reads
#define WKR 252   // worker blocks; 4 fps + 252 workers = 256 = one block per CU

typedef __attribute__((ext_vector_type(8))) short short8;
typedef __attribute__((ext_vector_type(4))) float f32x4;

__device__ __forceinline__ float rn_mul(float a, float b){ return __fmul_rn(a,b); }
__device__ __forceinline__ float rn_add(float a, float b){ return __fadd_rn(a,b); }
__device__ __forceinline__ float rn_sub(float a, float b){ return __fsub_rn(a,b); }

__device__ __forceinline__ unsigned short f2bf(float x){ // RNE f32->bf16
  union { float f; unsigned u; } v; v.f = x;
  unsigned r = v.u + 0x7fffu + ((v.u >> 16) & 1u);
  return (unsigned short)(r >> 16);
}

// v_max with a DPP-permuted copy; OOB/disabled lanes contribute 0 (safe: dists >= 0)
#define DPPMAX(m, ctrl) \
  m = fmaxf(m, __int_as_float(__builtin_amdgcn_update_dpp(0, __float_as_int(m), ctrl, 0xF, 0xF, true)))

// r11 structure + ONE change: 252 workers instead of 256, so total blocks = 256 =
// one per CU -> no CU hosts both an fps block and a worker block (the r11-r13
// slowdown mechanism: co-resident worker stealing fps issue slots + DS-pipe BW).
__global__ __launch_bounds__(256) void fused_kernel(
    const float* __restrict__ xyz, const float* __restrict__ feat,
    const float* __restrict__ rot,
    const float* __restrict__ W1, const float* __restrict__ b1,
    const float* __restrict__ W2, const float* __restrict__ b2,
    float* __restrict__ out,
    unsigned short* __restrict__ featT,
    unsigned short* __restrict__ Wp1, unsigned short* __restrict__ Wp2,
    int* __restrict__ gWidx, int* __restrict__ ftdone)
{
  __shared__ __align__(16) char shm[49664];
  const int gid = blockIdx.x;
  const int t = threadIdx.x;

  if (gid < B_){
    // ---------------- FPS: one block/batch, 4 waves x 16 pts (r9-exact core) ----------------
    __builtin_amdgcn_s_setprio(3);
    float*  xl    = (float*)shm;                          // 48 KB point store
    float4* cand  = (float4*)(shm + N_*3*4);              // [2][4] value+coords
    int*    candI = (int*)(shm + N_*3*4 + 8*16);          // [2][4] winner indices
    const int b = gid;
    const int lane = t & 63, w = t >> 6;                  // 4 waves
    const float* xb = xyz + (size_t)b*N_*3;
    {
      float4* dst = (float4*)xl; const float4* src = (const float4*)xb;
      for (int i = t; i < N_*3/4; i += 256) dst[i] = src[i];
    }
    __syncthreads();
    float px[16], py[16], pz[16], dist[16];
    {
      float buf[48];
      #pragma unroll
      for (int i=0;i<12;i++){
        const float4 v = *(const float4*)&xl[t*48 + i*4];
        buf[i*4+0]=v.x; buf[i*4+1]=v.y; buf[i*4+2]=v.z; buf[i*4+3]=v.w;
      }
      #pragma unroll
      for (int j=0;j<16;j++){
        px[j]=buf[j*3+0]; py[j]=buf[j*3+1]; pz[j]=buf[j*3+2];
        dist[j] = 1e10f;
      }
    }
    float cx = xl[0], cy = xl[1], cz = xl[2];             // farthest_0 = 0
    if (t == 0)
      __hip_atomic_store(&gWidx[b*P_ + 0], 0, __ATOMIC_RELAXED, __HIP_MEMORY_SCOPE_AGENT);
    for (int it=0; it<P_; ++it){
      float bestv = -1.f; int bestj = 0;
      #pragma unroll
      for (int j=0;j<16;j++){
        const float dx = rn_sub(px[j],cx), dy = rn_sub(py[j],cy), dz = rn_sub(pz[j],cz);
        const float d  = rn_add(rn_add(rn_mul(dx,dx), rn_mul(dy,dy)), rn_mul(dz,dz));
        const float nd = fminf(dist[j], d);
        dist[j] = nd;
        if (nd > bestv){ bestv = nd; bestj = j; }   // strict > keeps first (lowest j)
      }
      float m = bestv;
      DPPMAX(m, 0x111);  // row_shr:1
      DPPMAX(m, 0x112);  // row_shr:2
      DPPMAX(m, 0x114);  // row_shr:4
      DPPMAX(m, 0x118);  // row_shr:8
      DPPMAX(m, 0x142);  // row_bcast:15
      DPPMAX(m, 0x143);  // row_bcast:31
      const float ms = __int_as_float(__builtin_amdgcn_readlane(__float_as_int(m), 63));
      const unsigned long long bal = __ballot(bestv == ms);
      const int winlane = __ffsll((long long)bal) - 1;        // lowest lane = lowest index
      const int widx = __builtin_amdgcn_readlane(t*16 + bestj, winlane) & ~15;
      const int wj   = __builtin_amdgcn_readlane(bestj, winlane);
      const int pb = it & 1;                                   // double buffer (skew <= 1)
      if (lane == 0){
        const float* cp = xl + (size_t)(widx + wj)*3;
        cand[pb*4 + w] = make_float4(ms, cp[0], cp[1], cp[2]);
        candI[pb*4 + w] = widx + wj;
      }
      __syncthreads();
      // keep-first scan over 4 wave candidates (ascending wave id)
      const float4 c0 = cand[pb*4+0], c1 = cand[pb*4+1], c2 = cand[pb*4+2], c3 = cand[pb*4+3];
      const int i0 = candI[pb*4+0], i1 = candI[pb*4+1], i2 = candI[pb*4+2], i3 = candI[pb*4+3];
      float fv = c0.x; cx = c0.y; cy = c0.z; cz = c0.w; int fi = i0;
      if (c1.x > fv){ fv = c1.x; cx = c1.y; cy = c1.z; cz = c1.w; fi = i1; }
      if (c2.x > fv){ fv = c2.x; cx = c2.y; cy = c2.z; cz = c2.w; fi = i2; }
      if (c3.x > fv){ fv = c3.x; cx = c3.y; cy = c3.z; cz = c3.w; fi = i3; }
      if (t == 0 && it + 1 < P_)
        __hip_atomic_store(&gWidx[b*P_ + it + 1], fi, __ATOMIC_RELAXED, __HIP_MEMORY_SCOPE_AGENT);
    }
    __builtin_amdgcn_s_setprio(0);
  } else {
    // ================= worker block (252 of them, priority 0) =================
    const int wk = gid - B_;            // 0..251
    // ---- phase 1: feature transpose, strided tiles ----
    {
      float (*tile)[33] = (float (*)[33])shm;
      const int tx = t & 31, ty = t >> 5;  // 32x8
      for (int idx = wk; idx < 4096; idx += WKR){
        const int nx = idx & 127, cyi = (idx >> 7) & 7, bz = idx >> 10;
        const int n0 = nx*32, c0 = cyi*32;
        #pragma unroll
        for (int j=0;j<4;j++)
          tile[ty + j*8][tx] = feat[((size_t)bz*C_ + (size_t)(c0+ty+j*8))*N_ + n0 + tx];
        __syncthreads();
        #pragma unroll
        for (int j=0;j<4;j++)
          featT[((size_t)bz*N_ + (size_t)(n0+ty+j*8))*C_ + c0 + tx] = f2bf(tile[tx][ty + j*8]);
        __syncthreads();
      }
    }
    // ---- wprep rows (strided) ----
    for (int o = wk; o < 256; o += WKR){
      Wp1[o*288 + t] = f2bf(W1[o*259 + 3 + t]);
      if (t < 32){
        float v = (t < 3) ? W1[o*259 + t] : 0.f;
        Wp1[o*288 + 256 + t] = f2bf(v);
      }
      Wp2[o*256 + t] = f2bf(W2[o*256 + t]);
    }
    __threadfence();                     // write back dirty L2 lines (featT/Wp)
    __syncthreads();
    if (t == 0)
      __hip_atomic_fetch_add(ftdone, 1, __ATOMIC_RELEASE, __HIP_MEMORY_SCOPE_AGENT);

    // ---- phase 2 LDS layout ----
    unsigned short* Hlds = (unsigned short*)shm;                       // 33792 B
    int*            sI   = (int*)(shm + 64*HST*2);                     // 256 B
    unsigned short* rotP = (unsigned short*)(shm + 64*HST*2 + 256);    // 1024 B
    int*            sWi  = (int*)(shm + 64*HST*2 + 256 + 1024);        // 4 B

    const int lane = t & 63, wv = t >> 6;
    const int l15 = lane & 15, q = lane >> 4;
    bool ftOK = false;

    for (int u = wk; u < B_*P_; u += WKR){
      const int b = u & 3, p = u >> 2;   // consecutive u <-> publish order
      const int bp = b*P_ + p;
      // ---- wait for fps to publish centroid index p ----
      if (t == 0){
        int wi;
        while ((wi = __hip_atomic_load(&gWidx[bp], __ATOMIC_RELAXED, __HIP_MEMORY_SCOPE_AGENT)) == -1)
          __builtin_amdgcn_s_sleep(64);
        *sWi = wi;
      }
      __syncthreads();
      const int wi = *sWi;
      // ---- cylinder query (wave 0), outputs to LDS ----
      if (wv == 0){
        const float* xb = xyz + (size_t)b*N_*3;
        const float* r9 = rot + (size_t)bp*9;
        const float R0=r9[0],R1=r9[1],R2=r9[2],R3=r9[3],R4=r9[4],R5=r9[5],R6=r9[6],R7=r9[7],R8=r9[8];
        const float nx = xb[wi*3+0], ny = xb[wi*3+1], nz = xb[wi*3+2];
        const float thr = R2;   // replicate the reference's r2-shadowing bug
        int filled = 0;
        float p0r0=0.f, p0r1=0.f, p0r2=0.f;
        for (int base = 0; base < N_; base += 64){
          const int n = base + lane;
          const float dx = rn_sub(xb[n*3+0], nx);
          const float dy = rn_sub(xb[n*3+1], ny);
          const float dz = rn_sub(xb[n*3+2], nz);
          const float r0 = rn_add(rn_add(rn_mul(dx,R0), rn_mul(dy,R3)), rn_mul(dz,R6));
          const float r1 = rn_add(rn_add(rn_mul(dx,R1), rn_mul(dy,R4)), rn_mul(dz,R7));
          const float r2 = rn_add(rn_add(rn_mul(dx,R2), rn_mul(dy,R5)), rn_mul(dz,R8));
          if (base == 0){
            p0r0 = __shfl(r0, 0, 64); p0r1 = __shfl(r1, 0, 64); p0r2 = __shfl(r2, 0, 64);
          }
          const float d2 = rn_add(rn_mul(r1,r1), rn_mul(r2,r2));
          const bool mq = (d2 < thr) & (r0 > -0.02f) & (r0 < 0.04f);
          const unsigned long long bal = __ballot(mq);
          const int before = (int)__popcll(bal & ((1ull << lane) - 1ull));
          const int slot = filled + before;
          if (mq && slot < S_){
            sI[slot] = n;
            uint4 uu;
            uu.x = (unsigned)f2bf(r0) | ((unsigned)f2bf(r1) << 16);
            uu.y = (unsigned)f2bf(r2);
            uu.z = 0u; uu.w = 0u;
            *(uint4*)&rotP[slot*8] = uu;
          }
          filled += (int)__popcll(bal);
          if (filled >= S_) break;
        }
        if (filled < S_){
          const int slot = filled + lane;
          if (slot < S_){
            sI[slot] = 0;
            uint4 uu;
            uu.x = (unsigned)f2bf(p0r0) | ((unsigned)f2bf(p0r1) << 16);
            uu.y = (unsigned)f2bf(p0r2);
            uu.z = 0u; uu.w = 0u;
            *(uint4*)&rotP[slot*8] = uu;
          }
        }
      }
      __syncthreads();
      // ---- gate first mlp on featT/Wp completion (once per block) ----
      if (!ftOK){
        if (t == 0){
          while (__hip_atomic_load(ftdone, __ATOMIC_RELAXED, __HIP_MEMORY_SCOPE_AGENT) != WKR)
            __builtin_amdgcn_s_sleep(64);
        }
        __syncthreads();
        __builtin_amdgcn_fence(__ATOMIC_ACQUIRE, "agent");   // invalidate stale lines
        ftOK = true;
      }
      // ---- 1-pt MFMA mlp (bit-identical accumulation order to proven 2-pt kernel) ----
      {
        unsigned rowOff[4];
        #pragma unroll
        for (int st=0; st<4; ++st){
          const int s = st*16 + l15;
          const int row = sI[s];
          rowOff[st] = (unsigned)(((b*N_ + row)*C_ + q*8) * 2);
        }
        const char* fbase = (const char*)featT;
        f32x4 acc[4][4];
        #pragma unroll
        for (int at=0; at<4; ++at){
          const float4 bv = *(const float4*)(b1 + wv*64 + at*16 + q*4);
          #pragma unroll
          for (int st=0; st<4; ++st){
            acc[at][st][0]=bv.x; acc[at][st][1]=bv.y; acc[at][st][2]=bv.z; acc[at][st][3]=bv.w;
          }
        }
        const unsigned short* wb1 = Wp1 + (size_t)(wv*64 + l15)*288 + q*8;
        #pragma unroll
        for (int ks=0; ks<8; ++ks){
          short8 a[4], x[4];
          #pragma unroll
          for (int at=0; at<4; ++at) a[at] = *(const short8*)(wb1 + at*16*288 + ks*32);
          #pragma unroll
          for (int st=0; st<4; ++st) x[st] = *(const short8*)(fbase + rowOff[st] + ks*64);
          #pragma unroll
          for (int at=0; at<4; ++at)
            #pragma unroll
            for (int st=0; st<4; ++st)
              acc[at][st] = __builtin_amdgcn_mfma_f32_16x16x32_bf16(a[at], x[st], acc[at][st], 0,0,0);
        }
        { // K-step 8: rot fragments from LDS, rest zero
          short8 a[4], x[4];
          #pragma unroll
          for (int at=0; at<4; ++at) a[at] = *(const short8*)(wb1 + at*16*288 + 8*32);
          #pragma unroll
          for (int st=0; st<4; ++st){
            short8 v = (short8){0,0,0,0,0,0,0,0};
            if (q == 0) v = *(const short8*)&rotP[(st*16 + l15)*8];
            x[st] = v;
          }
          #pragma unroll
          for (int at=0; at<4; ++at)
            #pragma unroll
            for (int st=0; st<4; ++st)
              acc[at][st] = __builtin_amdgcn_mfma_f32_16x16x32_bf16(a[at], x[st], acc[at][st], 0,0,0);
        }
        // relu -> bf16 -> Hlds[s][o]
        #pragma unroll
        for (int at=0; at<4; ++at)
          #pragma unroll
          for (int st=0; st<4; ++st){
            const int s = st*16 + l15;
            const int o = wv*64 + at*16 + q*4;
            const unsigned h0 = f2bf(fmaxf(acc[at][st][0], 0.f));
            const unsigned h1 = f2bf(fmaxf(acc[at][st][1], 0.f));
            const unsigned h2 = f2bf(fmaxf(acc[at][st][2], 0.f));
            const unsigned h3 = f2bf(fmaxf(acc[at][st][3], 0.f));
            uint2 uu; uu.x = h0 | (h1 << 16); uu.y = h2 | (h3 << 16);
            *(uint2*)&Hlds[s*HST + o] = uu;
          }
        __syncthreads();
        // layer 2
        #pragma unroll
        for (int at=0; at<4; ++at){
          const float4 bv = *(const float4*)(b2 + wv*64 + at*16 + q*4);
          #pragma unroll
          for (int st=0; st<4; ++st){
            acc[at][st][0]=bv.x; acc[at][st][1]=bv.y; acc[at][st][2]=bv.z; acc[at][st][3]=bv.w;
          }
        }
        const unsigned short* wb2 = Wp2 + (size_t)(wv*64 + l15)*256 + q*8;
        #pragma unroll
        for (int ks=0; ks<8; ++ks){
          short8 a[4], h[4];
          #pragma unroll
          for (int at=0; at<4; ++at) a[at] = *(const short8*)(wb2 + at*16*256 + ks*32);
          #pragma unroll
          for (int st=0; st<4; ++st)
            h[st] = *(const short8*)&Hlds[(st*16 + l15)*HST + ks*32 + q*8];
          #pragma unroll
          for (int at=0; at<4; ++at)
            #pragma unroll
            for (int st=0; st<4; ++st)
              acc[at][st] = __builtin_amdgcn_mfma_f32_16x16x32_bf16(a[at], h[st], acc[at][st], 0,0,0);
        }
        // max over s, relu, store
        #pragma unroll
        for (int at=0; at<4; ++at){
          #pragma unroll
          for (int r=0; r<4; ++r){
            float mm = fmaxf(fmaxf(acc[at][0][r], acc[at][1][r]),
                             fmaxf(acc[at][2][r], acc[at][3][r]));
            mm = fmaxf(mm, __shfl_xor(mm, 1, 64));
            mm = fmaxf(mm, __shfl_xor(mm, 2, 64));
            mm = fmaxf(mm, __shfl_xor(mm, 4, 64));
            mm = fmaxf(mm, __shfl_xor(mm, 8, 64));
            mm = fmaxf(mm, 0.f);
            if (l15 == 0){
              const int o = wv*64 + at*16 + q*4 + r;
              out[((size_t)b*256 + o)*P_ + p] = mm;
            }
          }
        }
      }
      __syncthreads();   // before next unit reuses sI/rotP/Hlds
    }
  }
}

extern "C" void kernel_launch(void* const* d_in, const int* in_sizes, int n_in,
                              void* d_out, int out_size, void* d_ws, size_t ws_size,
                              hipStream_t stream)
{
  const float* xyz  = (const float*)d_in[0];
  const float* feat = (const float*)d_in[1];
  const float* rot  = (const float*)d_in[2];
  const float* W1   = (const float*)d_in[3];
  const float* b1   = (const float*)d_in[4];
  const float* W2   = (const float*)d_in[5];
  const float* b2   = (const float*)d_in[6];
  float* out = (float*)d_out;

  char* ws = (char*)d_ws;
  unsigned short* featT = (unsigned short*)(ws);
  size_t off = (size_t)B_*N_*C_*2;                                   // 8.39 MB
  unsigned short* Wp1 = (unsigned short*)(ws + off); off += (size_t)256*288*2;
  unsigned short* Wp2 = (unsigned short*)(ws + off); off += (size_t)256*256*2;
  int* gWidx  = (int*)(ws + off); off += (size_t)B_*P_*4;            // 16 KB
  int* ftdone = (int*)(ws + off); off += 16;
  (void)ws_size; (void)in_sizes; (void)n_in; (void)out_size;

  hipMemsetAsync(gWidx, 0xFF, (size_t)B_*P_*4, stream);   // -1 sentinels (deterministic)
  hipMemsetAsync(ftdone, 0, 4, stream);
  hipLaunchKernelGGL(fused_kernel, dim3(B_ + WKR), dim3(256), 0, stream,
                     xyz, feat, rot, W1, b1, W2, b2, out,
                     featT, Wp1, Wp2, gWidx, ftdone);
}

// Round 16
// 662.409 us; speedup vs baseline: 1.5845x; 1.0006x over previous
//
#include <hip/hip_runtime.h>
#include <hip/hip_bf16.h>

#define B_ 4
#define N_ 4096
#define C_ 256
#define P_ 1024
#define S_ 64
#define HST 264   // H LDS k-stride (bf16 elems); 528B rows -> 2-way (free) frag reads
#define WKR 252   // worker blocks; 4 fps + 252 workers = 256 = one block per CU

typedef __attribute__((ext_vector_type(8))) short short8;
typedef __attribute__((ext_vector_type(4))) float f32x4;

__device__ __forceinline__ float rn_mul(float a, float b){ return __fmul_rn(a,b); }
__device__ __forceinline__ float rn_add(float a, float b){ return __fadd_rn(a,b); }
__device__ __forceinline__ float rn_sub(float a, float b){ return __fsub_rn(a,b); }

__device__ __forceinline__ unsigned short f2bf(float x){ // RNE f32->bf16
  union { float f; unsigned u; } v; v.f = x;
  unsigned r = v.u + 0x7fffu + ((v.u >> 16) & 1u);
  return (unsigned short)(r >> 16);
}

// v_max with a DPP-permuted copy; OOB/disabled lanes contribute 0 (safe: dists >= 0)
#define DPPMAX(m, ctrl) \
  m = fmaxf(m, __int_as_float(__builtin_amdgcn_update_dpp(0, __float_as_int(m), ctrl, 0xF, 0xF, true)))

// r15 (662 us, CU-exclusive producer-consumer) + final micro-tweaks:
// s_sleep 64->8 (wake latency 1.7 -> 0.25 us), single merged memset (ftdone
// inits to -1; gate at WKR-1 after 252 increments).
__global__ __launch_bounds__(256) void fused_kernel(
    const float* __restrict__ xyz, const float* __restrict__ feat,
    const float* __restrict__ rot,
    const float* __restrict__ W1, const float* __restrict__ b1,
    const float* __restrict__ W2, const float* __restrict__ b2,
    float* __restrict__ out,
    unsigned short* __restrict__ featT,
    unsigned short* __restrict__ Wp1, unsigned short* __restrict__ Wp2,
    int* __restrict__ gWidx, int* __restrict__ ftdone)
{
  __shared__ __align__(16) char shm[49664];
  const int gid = blockIdx.x;
  const int t = threadIdx.x;

  if (gid < B_){
    // ---------------- FPS: one block/batch, 4 waves x 16 pts (r9-exact core) ----------------
    __builtin_amdgcn_s_setprio(3);
    float*  xl    = (float*)shm;                          // 48 KB point store
    float4* cand  = (float4*)(shm + N_*3*4);              // [2][4] value+coords
    int*    candI = (int*)(shm + N_*3*4 + 8*16);          // [2][4] winner indices
    const int b = gid;
    const int lane = t & 63, w = t >> 6;                  // 4 waves
    const float* xb = xyz + (size_t)b*N_*3;
    {
      float4* dst = (float4*)xl; const float4* src = (const float4*)xb;
      for (int i = t; i < N_*3/4; i += 256) dst[i] = src[i];
    }
    __syncthreads();
    float px[16], py[16], pz[16], dist[16];
    {
      float buf[48];
      #pragma unroll
      for (int i=0;i<12;i++){
        const float4 v = *(const float4*)&xl[t*48 + i*4];
        buf[i*4+0]=v.x; buf[i*4+1]=v.y; buf[i*4+2]=v.z; buf[i*4+3]=v.w;
      }
      #pragma unroll
      for (int j=0;j<16;j++){
        px[j]=buf[j*3+0]; py[j]=buf[j*3+1]; pz[j]=buf[j*3+2];
        dist[j] = 1e10f;
      }
    }
    float cx = xl[0], cy = xl[1], cz = xl[2];             // farthest_0 = 0
    if (t == 0)
      __hip_atomic_store(&gWidx[b*P_ + 0], 0, __ATOMIC_RELAXED, __HIP_MEMORY_SCOPE_AGENT);
    for (int it=0; it<P_; ++it){
      float bestv = -1.f; int bestj = 0;
      #pragma unroll
      for (int j=0;j<16;j++){
        const float dx = rn_sub(px[j],cx), dy = rn_sub(py[j],cy), dz = rn_sub(pz[j],cz);
        const float d  = rn_add(rn_add(rn_mul(dx,dx), rn_mul(dy,dy)), rn_mul(dz,dz));
        const float nd = fminf(dist[j], d);
        dist[j] = nd;
        if (nd > bestv){ bestv = nd; bestj = j; }   // strict > keeps first (lowest j)
      }
      float m = bestv;
      DPPMAX(m, 0x111);  // row_shr:1
      DPPMAX(m, 0x112);  // row_shr:2
      DPPMAX(m, 0x114);  // row_shr:4
      DPPMAX(m, 0x118);  // row_shr:8
      DPPMAX(m, 0x142);  // row_bcast:15
      DPPMAX(m, 0x143);  // row_bcast:31
      const float ms = __int_as_float(__builtin_amdgcn_readlane(__float_as_int(m), 63));
      const unsigned long long bal = __ballot(bestv == ms);
      const int winlane = __ffsll((long long)bal) - 1;        // lowest lane = lowest index
      const int widx = __builtin_amdgcn_readlane(t*16 + bestj, winlane) & ~15;
      const int wj   = __builtin_amdgcn_readlane(bestj, winlane);
      const int pb = it & 1;                                   // double buffer (skew <= 1)
      if (lane == 0){
        const float* cp = xl + (size_t)(widx + wj)*3;
        cand[pb*4 + w] = make_float4(ms, cp[0], cp[1], cp[2]);
        candI[pb*4 + w] = widx + wj;
      }
      __syncthreads();
      // keep-first scan over 4 wave candidates (ascending wave id)
      const float4 c0 = cand[pb*4+0], c1 = cand[pb*4+1], c2 = cand[pb*4+2], c3 = cand[pb*4+3];
      const int i0 = candI[pb*4+0], i1 = candI[pb*4+1], i2 = candI[pb*4+2], i3 = candI[pb*4+3];
      float fv = c0.x; cx = c0.y; cy = c0.z; cz = c0.w; int fi = i0;
      if (c1.x > fv){ fv = c1.x; cx = c1.y; cy = c1.z; cz = c1.w; fi = i1; }
      if (c2.x > fv){ fv = c2.x; cx = c2.y; cy = c2.z; cz = c2.w; fi = i2; }
      if (c3.x > fv){ fv = c3.x; cx = c3.y; cy = c3.z; cz = c3.w; fi = i3; }
      if (t == 0 && it + 1 < P_)
        __hip_atomic_store(&gWidx[b*P_ + it + 1], fi, __ATOMIC_RELAXED, __HIP_MEMORY_SCOPE_AGENT);
    }
    __builtin_amdgcn_s_setprio(0);
  } else {
    // ================= worker block (252 of them, priority 0) =================
    const int wk = gid - B_;            // 0..251
    // ---- phase 1: feature transpose, strided tiles ----
    {
      float (*tile)[33] = (float (*)[33])shm;
      const int tx = t & 31, ty = t >> 5;  // 32x8
      for (int idx = wk; idx < 4096; idx += WKR){
        const int nx = idx & 127, cyi = (idx >> 7) & 7, bz = idx >> 10;
        const int n0 = nx*32, c0 = cyi*32;
        #pragma unroll
        for (int j=0;j<4;j++)
          tile[ty + j*8][tx] = feat[((size_t)bz*C_ + (size_t)(c0+ty+j*8))*N_ + n0 + tx];
        __syncthreads();
        #pragma unroll
        for (int j=0;j<4;j++)
          featT[((size_t)bz*N_ + (size_t)(n0+ty+j*8))*C_ + c0 + tx] = f2bf(tile[tx][ty + j*8]);
        __syncthreads();
      }
    }
    // ---- wprep rows (strided) ----
    for (int o = wk; o < 256; o += WKR){
      Wp1[o*288 + t] = f2bf(W1[o*259 + 3 + t]);
      if (t < 32){
        float v = (t < 3) ? W1[o*259 + t] : 0.f;
        Wp1[o*288 + 256 + t] = f2bf(v);
      }
      Wp2[o*256 + t] = f2bf(W2[o*256 + t]);
    }
    __threadfence();                     // write back dirty L2 lines (featT/Wp)
    __syncthreads();
    if (t == 0)
      __hip_atomic_fetch_add(ftdone, 1, __ATOMIC_RELEASE, __HIP_MEMORY_SCOPE_AGENT);

    // ---- phase 2 LDS layout ----
    unsigned short* Hlds = (unsigned short*)shm;                       // 33792 B
    int*            sI   = (int*)(shm + 64*HST*2);                     // 256 B
    unsigned short* rotP = (unsigned short*)(shm + 64*HST*2 + 256);    // 1024 B
    int*            sWi  = (int*)(shm + 64*HST*2 + 256 + 1024);        // 4 B

    const int lane = t & 63, wv = t >> 6;
    const int l15 = lane & 15, q = lane >> 4;
    bool ftOK = false;

    for (int u = wk; u < B_*P_; u += WKR){
      const int b = u & 3, p = u >> 2;   // consecutive u <-> publish order
      const int bp = b*P_ + p;
      // ---- wait for fps to publish centroid index p ----
      if (t == 0){
        int wi;
        while ((wi = __hip_atomic_load(&gWidx[bp], __ATOMIC_RELAXED, __HIP_MEMORY_SCOPE_AGENT)) == -1)
          __builtin_amdgcn_s_sleep(8);
        *sWi = wi;
      }
      __syncthreads();
      const int wi = *sWi;
      // ---- cylinder query (wave 0), outputs to LDS ----
      if (wv == 0){
        const float* xb = xyz + (size_t)b*N_*3;
        const float* r9 = rot + (size_t)bp*9;
        const float R0=r9[0],R1=r9[1],R2=r9[2],R3=r9[3],R4=r9[4],R5=r9[5],R6=r9[6],R7=r9[7],R8=r9[8];
        const float nx = xb[wi*3+0], ny = xb[wi*3+1], nz = xb[wi*3+2];
        const float thr = R2;   // replicate the reference's r2-shadowing bug
        int filled = 0;
        float p0r0=0.f, p0r1=0.f, p0r2=0.f;
        for (int base = 0; base < N_; base += 64){
          const int n = base + lane;
          const float dx = rn_sub(xb[n*3+0], nx);
          const float dy = rn_sub(xb[n*3+1], ny);
          const float dz = rn_sub(xb[n*3+2], nz);
          const float r0 = rn_add(rn_add(rn_mul(dx,R0), rn_mul(dy,R3)), rn_mul(dz,R6));
          const float r1 = rn_add(rn_add(rn_mul(dx,R1), rn_mul(dy,R4)), rn_mul(dz,R7));
          const float r2 = rn_add(rn_add(rn_mul(dx,R2), rn_mul(dy,R5)), rn_mul(dz,R8));
          if (base == 0){
            p0r0 = __shfl(r0, 0, 64); p0r1 = __shfl(r1, 0, 64); p0r2 = __shfl(r2, 0, 64);
          }
          const float d2 = rn_add(rn_mul(r1,r1), rn_mul(r2,r2));
          const bool mq = (d2 < thr) & (r0 > -0.02f) & (r0 < 0.04f);
          const unsigned long long bal = __ballot(mq);
          const int before = (int)__popcll(bal & ((1ull << lane) - 1ull));
          const int slot = filled + before;
          if (mq && slot < S_){
            sI[slot] = n;
            uint4 uu;
            uu.x = (unsigned)f2bf(r0) | ((unsigned)f2bf(r1) << 16);
            uu.y = (unsigned)f2bf(r2);
            uu.z = 0u; uu.w = 0u;
            *(uint4*)&rotP[slot*8] = uu;
          }
          filled += (int)__popcll(bal);
          if (filled >= S_) break;
        }
        if (filled < S_){
          const int slot = filled + lane;
          if (slot < S_){
            sI[slot] = 0;
            uint4 uu;
            uu.x = (unsigned)f2bf(p0r0) | ((unsigned)f2bf(p0r1) << 16);
            uu.y = (unsigned)f2bf(p0r2);
            uu.z = 0u; uu.w = 0u;
            *(uint4*)&rotP[slot*8] = uu;
          }
        }
      }
      __syncthreads();
      // ---- gate first mlp on featT/Wp completion (once per block) ----
      if (!ftOK){
        if (t == 0){
          while (__hip_atomic_load(ftdone, __ATOMIC_RELAXED, __HIP_MEMORY_SCOPE_AGENT) != WKR - 1)
            __builtin_amdgcn_s_sleep(8);
        }
        __syncthreads();
        __builtin_amdgcn_fence(__ATOMIC_ACQUIRE, "agent");   // invalidate stale lines
        ftOK = true;
      }
      // ---- 1-pt MFMA mlp (bit-identical accumulation order to proven 2-pt kernel) ----
      {
        unsigned rowOff[4];
        #pragma unroll
        for (int st=0; st<4; ++st){
          const int s = st*16 + l15;
          const int row = sI[s];
          rowOff[st] = (unsigned)(((b*N_ + row)*C_ + q*8) * 2);
        }
        const char* fbase = (const char*)featT;
        f32x4 acc[4][4];
        #pragma unroll
        for (int at=0; at<4; ++at){
          const float4 bv = *(const float4*)(b1 + wv*64 + at*16 + q*4);
          #pragma unroll
          for (int st=0; st<4; ++st){
            acc[at][st][0]=bv.x; acc[at][st][1]=bv.y; acc[at][st][2]=bv.z; acc[at][st][3]=bv.w;
          }
        }
        const unsigned short* wb1 = Wp1 + (size_t)(wv*64 + l15)*288 + q*8;
        #pragma unroll
        for (int ks=0; ks<8; ++ks){
          short8 a[4], x[4];
          #pragma unroll
          for (int at=0; at<4; ++at) a[at] = *(const short8*)(wb1 + at*16*288 + ks*32);
          #pragma unroll
          for (int st=0; st<4; ++st) x[st] = *(const short8*)(fbase + rowOff[st] + ks*64);
          #pragma unroll
          for (int at=0; at<4; ++at)
            #pragma unroll
            for (int st=0; st<4; ++st)
              acc[at][st] = __builtin_amdgcn_mfma_f32_16x16x32_bf16(a[at], x[st], acc[at][st], 0,0,0);
        }
        { // K-step 8: rot fragments from LDS, rest zero
          short8 a[4], x[4];
          #pragma unroll
          for (int at=0; at<4; ++at) a[at] = *(const short8*)(wb1 + at*16*288 + 8*32);
          #pragma unroll
          for (int st=0; st<4; ++st){
            short8 v = (short8){0,0,0,0,0,0,0,0};
            if (q == 0) v = *(const short8*)&rotP[(st*16 + l15)*8];
            x[st] = v;
          }
          #pragma unroll
          for (int at=0; at<4; ++at)
            #pragma unroll
            for (int st=0; st<4; ++st)
              acc[at][st] = __builtin_amdgcn_mfma_f32_16x16x32_bf16(a[at], x[st], acc[at][st], 0,0,0);
        }
        // relu -> bf16 -> Hlds[s][o]
        #pragma unroll
        for (int at=0; at<4; ++at)
          #pragma unroll
          for (int st=0; st<4; ++st){
            const int s = st*16 + l15;
            const int o = wv*64 + at*16 + q*4;
            const unsigned h0 = f2bf(fmaxf(acc[at][st][0], 0.f));
            const unsigned h1 = f2bf(fmaxf(acc[at][st][1], 0.f));
            const unsigned h2 = f2bf(fmaxf(acc[at][st][2], 0.f));
            const unsigned h3 = f2bf(fmaxf(acc[at][st][3], 0.f));
            uint2 uu; uu.x = h0 | (h1 << 16); uu.y = h2 | (h3 << 16);
            *(uint2*)&Hlds[s*HST + o] = uu;
          }
        __syncthreads();
        // layer 2
        #pragma unroll
        for (int at=0; at<4; ++at){
          const float4 bv = *(const float4*)(b2 + wv*64 + at*16 + q*4);
          #pragma unroll
          for (int st=0; st<4; ++st){
            acc[at][st][0]=bv.x; acc[at][st][1]=bv.y; acc[at][st][2]=bv.z; acc[at][st][3]=bv.w;
          }
        }
        const unsigned short* wb2 = Wp2 + (size_t)(wv*64 + l15)*256 + q*8;
        #pragma unroll
        for (int ks=0; ks<8; ++ks){
          short8 a[4], h[4];
          #pragma unroll
          for (int at=0; at<4; ++at) a[at] = *(const short8*)(wb2 + at*16*256 + ks*32);
          #pragma unroll
          for (int st=0; st<4; ++st)
            h[st] = *(const short8*)&Hlds[(st*16 + l15)*HST + ks*32 + q*8];
          #pragma unroll
          for (int at=0; at<4; ++at)
            #pragma unroll
            for (int st=0; st<4; ++st)
              acc[at][st] = __builtin_amdgcn_mfma_f32_16x16x32_bf16(a[at], h[st], acc[at][st], 0,0,0);
        }
        // max over s, relu, store
        #pragma unroll
        for (int at=0; at<4; ++at){
          #pragma unroll
          for (int r=0; r<4; ++r){
            float mm = fmaxf(fmaxf(acc[at][0][r], acc[at][1][r]),
                             fmaxf(acc[at][2][r], acc[at][3][r]));
            mm = fmaxf(mm, __shfl_xor(mm, 1, 64));
            mm = fmaxf(mm, __shfl_xor(mm, 2, 64));
            mm = fmaxf(mm, __shfl_xor(mm, 4, 64));
            mm = fmaxf(mm, __shfl_xor(mm, 8, 64));
            mm = fmaxf(mm, 0.f);
            if (l15 == 0){
              const int o = wv*64 + at*16 + q*4 + r;
              out[((size_t)b*256 + o)*P_ + p] = mm;
            }
          }
        }
      }
      __syncthreads();   // before next unit reuses sI/rotP/Hlds
    }
  }
}

extern "C" void kernel_launch(void* const* d_in, const int* in_sizes, int n_in,
                              void* d_out, int out_size, void* d_ws, size_t ws_size,
                              hipStream_t stream)
{
  const float* xyz  = (const float*)d_in[0];
  const float* feat = (const float*)d_in[1];
  const float* rot  = (const float*)d_in[2];
  const float* W1   = (const float*)d_in[3];
  const float* b1   = (const float*)d_in[4];
  const float* W2   = (const float*)d_in[5];
  const float* b2   = (const float*)d_in[6];
  float* out = (float*)d_out;

  char* ws = (char*)d_ws;
  unsigned short* featT = (unsigned short*)(ws);
  size_t off = (size_t)B_*N_*C_*2;                                   // 8.39 MB
  unsigned short* Wp1 = (unsigned short*)(ws + off); off += (size_t)256*288*2;
  unsigned short* Wp2 = (unsigned short*)(ws + off); off += (size_t)256*256*2;
  int* gWidx  = (int*)(ws + off); off += (size_t)B_*P_*4;            // 16 KB
  int* ftdone = (int*)(ws + off); off += 16;                         // contiguous with gWidx
  (void)ws_size; (void)in_sizes; (void)n_in; (void)out_size;

  // single memset: gWidx sentinels = -1 AND ftdone = -1 (gate at WKR-1 after 252 adds)
  hipMemsetAsync(gWidx, 0xFF, (size_t)B_*P_*4 + 16, stream);
  hipLaunchKernelGGL(fused_kernel, dim3(B_ + WKR), dim3(256), 0, stream,
                     xyz, feat, rot, W1, b1, W2, b2, out,
                     featT, Wp1, Wp2, gWidx, ftdone);
}